// Round 4
// baseline (38.047 us; speedup 1.0000x reference)
//
#include <hip/hip_runtime.h>

// Problem constants (from reference): B=32, S=256, C=50, L=20, F=30, W=3
constexpr int Bc = 32;
constexpr int Sc = 256;
constexpr int Cc = 50;
constexpr int Lc = 20;
constexpr int Fc = 30;
constexpr int Wc = 3;
constexpr int OUT_CH   = Cc * Fc;       // 1500
constexpr int CONV_LEN = Lc - Wc + 1;   // 18
constexpr int XSZ      = Cc * Lc;       // 1000 floats per (b,s)
constexpr int BLOCK    = 256;
constexpr int CH_PER_T = 6;             // 6t..6t+5 never crosses a group boundary
constexpr int NP       = 4;             // positions per block (weights amortized 4x)

// No LDS, no barriers: each thread streams its own 80B row straight from
// global (the 5 threads sharing a row hit the same L1 lines), computes 6
// channels, stores. Waves are independent -> pure latency-hiding via TLP/ILP.
__global__ __launch_bounds__(BLOCK, 4)
void charcnn_kernel(const float* __restrict__ x,      // [B*S, C, L]
                    const float* __restrict__ weight, // [C*F, 1, W]
                    const float* __restrict__ bias,   // [C*F]
                    float* __restrict__ out)          // [B*S, C*F]
{
    const int t = threadIdx.x;
    if (t >= OUT_CH / CH_PER_T) return;   // 250 active lanes; no barriers -> safe

    const int pos0 = blockIdx.x * NP;
    const int c    = t / 5;               // group shared by this thread's 6 channels

    // ---- weights/bias once per thread (register-resident across NP positions)
    float w[CH_PER_T * Wc];               // 18 contiguous floats -> 9x float2
    float bb[CH_PER_T];                   // 6 contiguous floats  -> 3x float2
    {
        const float2* wp = (const float2*)(weight + t * (CH_PER_T * Wc));
        #pragma unroll
        for (int i = 0; i < (CH_PER_T * Wc) / 2; ++i) {
            const float2 q = wp[i];
            w[2*i] = q.x; w[2*i+1] = q.y;
        }
        const float2* bp = (const float2*)(bias + t * CH_PER_T);
        #pragma unroll
        for (int i = 0; i < CH_PER_T / 2; ++i) {
            const float2 q = bp[i];
            bb[2*i] = q.x; bb[2*i+1] = q.y;
        }
    }

    const float* xrow = x + (size_t)pos0 * XSZ + c * Lc;  // 16B-aligned (80B rows)

    #pragma unroll 2                      // lets iter p+1 loads issue under iter p compute
    for (int p = 0; p < NP; ++p) {
        // Row: 80 B -> 5x global_load_dwordx4 (L1-shared among the 5 sibling threads).
        float v[Lc];
        {
            const float4* rv = (const float4*)(xrow + (size_t)p * XSZ);
            #pragma unroll
            for (int i = 0; i < Lc / 4; ++i) {
                const float4 q = rv[i];
                v[4*i+0] = q.x; v[4*i+1] = q.y; v[4*i+2] = q.z; v[4*i+3] = q.w;
            }
        }

        float res[CH_PER_T];
        #pragma unroll
        for (int j = 0; j < CH_PER_T; ++j) {
            const float w0 = w[3*j + 0];
            const float w1 = w[3*j + 1];
            const float w2 = w[3*j + 2];

            float cv[CONV_LEN];
            #pragma unroll
            for (int q = 0; q < CONV_LEN; ++q)
                cv[q] = fmaf(v[q], w0, fmaf(v[q+1], w1, v[q+2] * w2));

            // Max via v_max3 fusion: 18 values in ~9 insts.
            float m = fmaxf(fmaxf(cv[0], cv[1]), cv[2]);
            #pragma unroll
            for (int q = 3; q + 1 < CONV_LEN; q += 2)
                m = fmaxf(fmaxf(m, cv[q]), cv[q+1]);
            m = fmaxf(m, cv[CONV_LEN - 1]);

            res[j] = m + bb[j];           // bias invariant over window: hoisted past max
        }

        // 6 floats at out + (pos0+p)*1500 + 6t: contiguous across lanes.
        float* op = out + (size_t)(pos0 + p) * OUT_CH + t * CH_PER_T;
        #pragma unroll
        for (int i = 0; i < CH_PER_T / 2; ++i)
            ((float2*)op)[i] = make_float2(res[2*i], res[2*i+1]);
    }
}

extern "C" void kernel_launch(void* const* d_in, const int* in_sizes, int n_in,
                              void* d_out, int out_size, void* d_ws, size_t ws_size,
                              hipStream_t stream) {
    const float* x      = (const float*)d_in[0];  // [B,S,C,L] fp32
    const float* weight = (const float*)d_in[1];  // [C*F,1,W] fp32
    const float* bias   = (const float*)d_in[2];  // [C*F] fp32
    float* out          = (float*)d_out;          // [B,S,C*F] fp32

    const int nBlocks = (Bc * Sc) / NP;           // 2048 blocks
    charcnn_kernel<<<nBlocks, BLOCK, 0, stream>>>(x, weight, bias, out);
}

// Round 5
// 29.272 us; speedup vs baseline: 1.2998x; 1.2998x over previous
//
#include <hip/hip_runtime.h>

// Problem constants (from reference): B=32, S=256, C=50, L=20, F=30, W=3
constexpr int Bc = 32;
constexpr int Sc = 256;
constexpr int Cc = 50;
constexpr int Lc = 20;
constexpr int Fc = 30;
constexpr int Wc = 3;
constexpr int OUT_CH   = Cc * Fc;       // 1500
constexpr int CONV_LEN = Lc - Wc + 1;   // 18
constexpr int XSZ      = Cc * Lc;       // 1000 floats per (b,s)
constexpr int BLOCK    = 256;
constexpr int CH_PER_T = 6;             // 6t..6t+5 never crosses a group boundary
constexpr int NP       = 4;             // positions per block
constexpr int ACT      = OUT_CH / CH_PER_T;   // 250 active lanes (== XSZ/4 stagers)

// Raw barrier WITHOUT vmcnt(0): __syncthreads() drains all in-flight global
// loads (s_waitcnt vmcnt(0) before s_barrier), which serialized every prior
// version. lgkmcnt(0) alone is sufficient: it retires this wave's own ds_write
// (visibility) and ds_read (WAR on the buffer). Global prefetch loads stay in
// flight across the barrier and are vmcnt-waited by the compiler at their use.
static __device__ __forceinline__ void block_sync() {
    asm volatile("s_waitcnt lgkmcnt(0)" ::: "memory");
    __builtin_amdgcn_s_barrier();
    asm volatile("" ::: "memory");
}

__global__ __launch_bounds__(BLOCK, 4)
void charcnn_kernel(const float* __restrict__ x,      // [B*S, C, L]
                    const float* __restrict__ weight, // [C*F, 1, W]
                    const float* __restrict__ bias,   // [C*F]
                    float* __restrict__ out)          // [B*S, C*F]
{
    __shared__ float xs[2][XSZ];        // double-buffered 4 KB slabs

    const int t    = threadIdx.x;
    const int pos0 = blockIdx.x * NP;
    const bool on  = (t < ACT);         // same 250 lanes stage and compute

    // ---- weights/bias once per thread (register-resident across NP positions)
    float w[CH_PER_T * Wc];             // 18 contiguous floats -> 9x float2
    float bb[CH_PER_T];                 // 6 contiguous floats  -> 3x float2
    if (on) {
        const float2* wp = (const float2*)(weight + t * (CH_PER_T * Wc));
        #pragma unroll
        for (int i = 0; i < (CH_PER_T * Wc) / 2; ++i) {
            const float2 q = wp[i];
            w[2*i] = q.x; w[2*i+1] = q.y;
        }
        const float2* bp = (const float2*)(bias + t * CH_PER_T);
        #pragma unroll
        for (int i = 0; i < CH_PER_T / 2; ++i) {
            const float2 q = bp[i];
            bb[2*i] = q.x; bb[2*i+1] = q.y;
        }
    }

    const int c = t / 5;                // group shared by this thread's 6 channels

    // ---- prologue: slab0 -> xs[0]; slab1 held in preA (written at end of p=0)
    float4 preA, preB;
    if (on) {
        float4 s0 = ((const float4*)(x + (size_t)(pos0 + 0) * XSZ))[t];
        preA      = ((const float4*)(x + (size_t)(pos0 + 1) * XSZ))[t];
        ((float4*)xs[0])[t] = s0;       // compiler: vmcnt leaves preA in flight
    }
    block_sync();

    #pragma unroll
    for (int p = 0; p < NP; ++p) {
        const int buf = p & 1;

        // Issue the load for position p+2 EARLY: it stays in flight through
        // TWO compute phases (ds_write at end of p+1), ~1700 cycles of cover.
        if (on && (p + 2 < NP))
            preB = ((const float4*)(x + (size_t)(pos0 + p + 2) * XSZ))[t];

        float res[CH_PER_T];
        if (on) {
            // Row: 80 B, 16B-aligned -> 5x ds_read_b128.
            float v[Lc];
            const float4* rowv = (const float4*)(xs[buf] + c * Lc);
            #pragma unroll
            for (int i = 0; i < Lc / 4; ++i) {
                const float4 q = rowv[i];
                v[4*i+0] = q.x; v[4*i+1] = q.y; v[4*i+2] = q.z; v[4*i+3] = q.w;
            }

            #pragma unroll
            for (int j = 0; j < CH_PER_T; ++j) {
                const float w0 = w[3*j + 0];
                const float w1 = w[3*j + 1];
                const float w2 = w[3*j + 2];

                // Running max, two conv values per step -> v_max3 fusion.
                float m = fmaf(v[0], w0, fmaf(v[1], w1, v[2] * w2));
                #pragma unroll
                for (int q = 1; q + 1 < CONV_LEN; q += 2) {
                    const float a = fmaf(v[q],   w0, fmaf(v[q+1], w1, v[q+2] * w2));
                    const float b = fmaf(v[q+1], w0, fmaf(v[q+2], w1, v[q+3] * w2));
                    m = fmaxf(fmaxf(m, a), b);
                }
                const float a = fmaf(v[CONV_LEN-1], w0,
                                fmaf(v[CONV_LEN],   w1, v[CONV_LEN+1] * w2));
                m = fmaxf(m, a);

                res[j] = m + bb[j];     // bias invariant over window: hoisted past max
            }

            // Stage slab p+1 into the other buffer; compiler waits ONLY its load.
            if (p + 1 < NP)
                ((float4*)xs[buf ^ 1])[t] = preA;

            // 6 floats at out + (pos0+p)*1500 + 6t: contiguous across lanes.
            float* op = out + (size_t)(pos0 + p) * OUT_CH + t * CH_PER_T;
            #pragma unroll
            for (int i = 0; i < CH_PER_T / 2; ++i)
                ((float2*)op)[i] = make_float2(res[2*i], res[2*i+1]);

            preA = preB;                // slab p+2 becomes next to stage
        }

        if (p + 1 < NP) block_sync();   // lgkmcnt-only barrier: prefetch survives
    }
}

extern "C" void kernel_launch(void* const* d_in, const int* in_sizes, int n_in,
                              void* d_out, int out_size, void* d_ws, size_t ws_size,
                              hipStream_t stream) {
    const float* x      = (const float*)d_in[0];  // [B,S,C,L] fp32
    const float* weight = (const float*)d_in[1];  // [C*F,1,W] fp32
    const float* bias   = (const float*)d_in[2];  // [C*F] fp32
    float* out          = (float*)d_out;          // [B,S,C*F] fp32

    const int nBlocks = (Bc * Sc) / NP;           // 2048 blocks
    charcnn_kernel<<<nBlocks, BLOCK, 0, stream>>>(x, weight, bias, out);
}